// Round 11
// baseline (80.740 us; speedup 1.0000x reference)
//
#include <hip/hip_runtime.h>

// 3D median 3x3x3, zero pad, exact. Round 11: LDS PLANE STAGING.
// R9 diag: VALUBusy 46%, VALU-floor 10.9us vs 24.6 actual; R10 (reg
// prefetch) neutral -> stall is L1 bandwidth: 54 VMEM/thread, scalar halo
// loads cost full 1KB wave-footprint each, 3x redundancy (y-halo rows
// re-read by neighbor ty, x-halo re-reads same lines). Fix: stage each
// plane's 6x256-float tile in LDS once per block (coalesced, unique bytes),
// read rows+halos from LDS (idle pipe, 2-way bank aliasing = free).
// 2 slots ping-pong, 1 barrier/z-iter; next plane's global loads issued
// AFTER the barrier so the next barrier's vmcnt(0) drain finds them done.
// Selection math unchanged (absmax 0.0, R1-R10): y-sort -> z-sort ->
// band-stat prune 19 -> antichain exclusions -> triple forgetful -> med9.

#define MIN3(a, b, c) fminf(fminf(a, b), c)
#define MAX3(a, b, c) fmaxf(fmaxf(a, b), c)
#define MED3(a, b, c) __builtin_amdgcn_fmed3f(a, b, c)

__device__ __forceinline__ void sort3(float &a, float &b, float &c) {
    float lo = MIN3(a, b, c);
    float hi = MAX3(a, b, c);
    float md = MED3(a, b, c);
    a = lo; b = md; c = hi;
}

__device__ __forceinline__ float sel19(const float V[9][6], int o) {
    float a0h = MAX3(V[0][o], V[0][o + 1], V[0][o + 2]);
    float a1m = MED3(V[1][o], V[1][o + 1], V[1][o + 2]);
    float a1h = MAX3(V[1][o], V[1][o + 1], V[1][o + 2]);
    float a2l = V[2][o], a2m = V[2][o + 1], a2h = V[2][o + 2];
    sort3(a2l, a2m, a2h);
    float b0m = MED3(V[3][o], V[3][o + 1], V[3][o + 2]);
    float b0h = MAX3(V[3][o], V[3][o + 1], V[3][o + 2]);
    float b1l = V[4][o], b1m = V[4][o + 1], b1h = V[4][o + 2];
    sort3(b1l, b1m, b1h);
    float b2l = MIN3(V[5][o], V[5][o + 1], V[5][o + 2]);
    float b2m = MED3(V[5][o], V[5][o + 1], V[5][o + 2]);
    float c0l = V[6][o], c0m = V[6][o + 1], c0h = V[6][o + 2];
    sort3(c0l, c0m, c0h);
    float c1l = MIN3(V[7][o], V[7][o + 1], V[7][o + 2]);
    float c1m = MED3(V[7][o], V[7][o + 1], V[7][o + 2]);
    float c2l = MIN3(V[8][o], V[8][o + 1], V[8][o + 2]);

    float pa = a1m, pb = b0m, pc = b1l; sort3(pa, pb, pc);  // pa <= med
    float qa = b1h, qb = b2m, qc = c1m; sort3(qa, qb, qc);  // qc >= med
    float ra = a0h, rb = a2l, rc = c0l; sort3(ra, rb, rc);  // ra <= med
    float sa = a2h, sb = c0h, sc = c2l; sort3(sa, sb, sc);  // sc >= med
    (void)pa; (void)qc; (void)ra; (void)sc;

    float t1l = pb, t1m = pc, t1h = b1m;                    // free-sorted
    float t2l = rb, t2m = rc, t2h = a1h; sort3(t2l, t2m, t2h);
    float t3l = sa, t3m = sb, t3h = c1l; sort3(t3l, t3m, t3h);
    {
        float lam1 = MED3(t1l, t2l, t3l), lam2 = MAX3(t1l, t2l, t3l);
        float eta1 = MIN3(t1h, t2h, t3h), eta2 = MED3(t1h, t2h, t3h);
        float mu1 = t1m, mu2 = t2m, mu3 = t3m;
        t1l = lam1; t1m = lam2; t1h = qa; sort3(t1l, t1m, t1h);
        t2l = mu1;  t2m = mu2;  t2h = mu3; sort3(t2l, t2m, t2h);
        t3l = eta1; t3m = eta2; t3h = qb; sort3(t3l, t3m, t3h);
    }
    {
        float lam1 = MED3(t1l, t2l, t3l), lam2 = MAX3(t1l, t2l, t3l);
        float eta1 = MIN3(t1h, t2h, t3h), eta2 = MED3(t1h, t2h, t3h);
        float mu1 = t1m, mu2 = t2m, mu3 = t3m;
        t1l = lam1; t1m = lam2; t1h = a2m; sort3(t1l, t1m, t1h);
        t2l = mu1;  t2m = mu2;  t2h = mu3; sort3(t2l, t2m, t2h);
        t3l = eta1; t3m = eta2; t3h = c0m; sort3(t3l, t3m, t3h);
    }
    {
        float lam1 = MED3(t1l, t2l, t3l), lam2 = MAX3(t1l, t2l, t3l);
        float eta1 = MIN3(t1h, t2h, t3h), eta2 = MED3(t1h, t2h, t3h);
        float mu1 = t1m, mu2 = t2m, mu3 = t3m;
        t1l = lam1; t1m = lam2; t1h = b0h; sort3(t1l, t1m, t1h);
        t2l = mu1;  t2m = mu2;  t2h = mu3; sort3(t2l, t2m, t2h);
        t3l = eta1; t3m = eta2; t3h = b2l; sort3(t3l, t3m, t3h);
    }
    return MED3(MAX3(t1l, t2l, t3l), MED3(t1m, t2m, t3m),
                MIN3(t1h, t2h, t3h));
}

__global__ __launch_bounds__(256) void median3d_kernel(
    const float *__restrict__ x, float *__restrict__ out) {
    const int W = 256, H = 256, D = 64;
    const int lane = threadIdx.x;       // wave spans full 256-wide x row
    const int ty = threadIdx.y;         // 0..3; wave-uniform
    const int w0 = lane << 2;           // 4 x-outputs
    const int h = blockIdx.y * 4 + ty;
    const int d0 = blockIdx.z * 4;      // 4 z-outputs
    const int gh0 = blockIdx.y * 4 - 1; // first staged row (global)
    const int t = ty * 64 + lane;       // linear thread id
    const int wl = (lane == 0) ? 0 : (w0 - 1);
    const int wr = (lane == 63) ? (W - 1) : (w0 + 4);
    const bool lval = (lane != 0), rval = (lane != 63);

    // 2 ping-pong plane slots, 6 rows x 256 floats each (12 KB).
    __shared__ float lds[2][6 * 256];

    float Yst[3][3][6];
    float4 sA0, sA1, sB0, sB1;  // staging regs (2 float4/thread)

    // --- Coalesced global load of plane q (dd=d0+q) into staging regs.
    // Thread t covers float4 #t (row ty) and, for ty<2, #(256+t) (row 4+ty).
#define STAGE_LOAD(Q, V0, V1)                                                \
    do {                                                                     \
        const int dd = d0 + (Q);                                             \
        const bool zok = (unsigned)dd < (unsigned)D;                         \
        const int dc = zok ? dd : 0;                                         \
        const int hh0 = gh0 + ty;                                            \
        const bool ok0 = zok && ((unsigned)hh0 < (unsigned)H);               \
        const int hc0 = ((unsigned)hh0 < (unsigned)H) ? hh0 : 0;             \
        const float4 z4 = make_float4(0.f, 0.f, 0.f, 0.f);                   \
        V0 = ok0 ? *(const float4 *)(x + (size_t)(dc * H + hc0) * W + w0)    \
                 : z4;                                                       \
        V1 = z4;                                                             \
        if (ty < 2) { /* wave-uniform */                                     \
            const int hh1 = gh0 + 4 + ty;                                    \
            const bool ok1 = zok && ((unsigned)hh1 < (unsigned)H);           \
            const int hc1 = ((unsigned)hh1 < (unsigned)H) ? hh1 : 0;         \
            V1 = ok1 ? *(const float4 *)(x + (size_t)(dc * H + hc1) * W + w0)\
                     : z4;                                                   \
        }                                                                    \
    } while (0)

#define STAGE_WRITE(SLOT, V0, V1)                                            \
    do {                                                                     \
        ((float4 *)lds[SLOT])[t] = V0;                                       \
        if (ty < 2) ((float4 *)lds[SLOT])[256 + t] = V1;                     \
    } while (0)

    // --- Read my 3 rows (+x halos) of a staged plane, y-sort into Yst.
#define LDS_YSORT(SLOT, YSLOT)                                               \
    do {                                                                     \
        float r_[3][6];                                                      \
        _Pragma("unroll") for (int dy = 0; dy < 3; ++dy) {                   \
            const int ro = (ty + dy) * 256;                                  \
            const float l = lds[SLOT][ro + wl];                              \
            const float4 m = *(const float4 *)&lds[SLOT][ro + w0];           \
            const float rr = lds[SLOT][ro + wr];                             \
            r_[dy][0] = lval ? l : 0.0f;                                     \
            r_[dy][1] = m.x; r_[dy][2] = m.y;                                \
            r_[dy][3] = m.z; r_[dy][4] = m.w;                                \
            r_[dy][5] = rval ? rr : 0.0f;                                    \
        }                                                                    \
        _Pragma("unroll") for (int c = 0; c < 6; ++c) {                      \
            sort3(r_[0][c], r_[1][c], r_[2][c]);                             \
            Yst[YSLOT][0][c] = r_[0][c];                                     \
            Yst[YSLOT][1][c] = r_[1][c];                                     \
            Yst[YSLOT][2][c] = r_[2][c];                                     \
        }                                                                    \
    } while (0)

    // --- Direct (unstaged) load+y-sort for prologue planes q=-1,0.
#define LOADDIRECT(Q, YSLOT)                                                 \
    do {                                                                     \
        const int dd = d0 + (Q);                                             \
        const bool zok = (unsigned)dd < (unsigned)D;                         \
        const int dc = zok ? dd : 0;                                         \
        float r_[3][6];                                                      \
        _Pragma("unroll") for (int dy = 0; dy < 3; ++dy) {                   \
            const int hh = h + dy - 1;                                       \
            const bool hok = (unsigned)hh < (unsigned)H;                     \
            const int hc = hok ? hh : 0;                                     \
            const bool ok = zok && hok;                                      \
            const float *rowp = x + (size_t)(dc * H + hc) * W;               \
            const float l = rowp[wl];                                        \
            const float4 m = *(const float4 *)(rowp + w0);                   \
            const float rr = rowp[wr];                                       \
            r_[dy][0] = (ok && lval) ? l : 0.0f;                             \
            r_[dy][1] = ok ? m.x : 0.0f;                                     \
            r_[dy][2] = ok ? m.y : 0.0f;                                     \
            r_[dy][3] = ok ? m.z : 0.0f;                                     \
            r_[dy][4] = ok ? m.w : 0.0f;                                     \
            r_[dy][5] = (ok && rval) ? rr : 0.0f;                            \
        }                                                                    \
        _Pragma("unroll") for (int c = 0; c < 6; ++c) {                      \
            sort3(r_[0][c], r_[1][c], r_[2][c]);                             \
            Yst[YSLOT][0][c] = r_[0][c];                                     \
            Yst[YSLOT][1][c] = r_[1][c];                                     \
            Yst[YSLOT][2][c] = r_[2][c];                                     \
        }                                                                    \
    } while (0)

#define WINDOW(SA, SB, SC, DOUT)                                             \
    do {                                                                     \
        float V[9][6];                                                       \
        _Pragma("unroll") for (int yr = 0; yr < 3; ++yr)                     \
            _Pragma("unroll") for (int c = 0; c < 6; ++c) {                  \
                float a = Yst[SA][yr][c];                                    \
                float b = Yst[SB][yr][c];                                    \
                float cc = Yst[SC][yr][c];                                   \
                sort3(a, b, cc);                                             \
                V[0 + yr][c] = a;                                            \
                V[3 + yr][c] = b;                                            \
                V[6 + yr][c] = cc;                                           \
            }                                                                \
        float4 r4;                                                           \
        r4.x = sel19(V, 0);                                                  \
        r4.y = sel19(V, 1);                                                  \
        r4.z = sel19(V, 2);                                                  \
        r4.w = sel19(V, 3);                                                  \
        *(float4 *)(out + (size_t)((DOUT)*H + h) * W + w0) = r4;             \
    } while (0)

    // ---- Prologue: plane1 -> LDS slot1; prefetch plane2; planes -1,0 direct.
    STAGE_LOAD(1, sA0, sA1);
    STAGE_WRITE(1, sA0, sA1);
    STAGE_LOAD(2, sB0, sB1);   // long in-flight; drained by iter0 barrier
    LOADDIRECT(-1, 0);         // Yst0 = plane -1
    LOADDIRECT(0, 1);          // Yst1 = plane 0

    // ---- zo=0 (planes -1,0,1 -> out d0)
    __syncthreads();
    STAGE_WRITE(0, sB0, sB1);  // plane 2 -> slot 0
    STAGE_LOAD(3, sA0, sA1);   // prefetch plane 3 (after barrier)
    LDS_YSORT(1, 2);           // Yst2 = plane 1
    WINDOW(0, 1, 2, d0 + 0);

    // ---- zo=1 (planes 0,1,2 -> out d0+1)
    __syncthreads();
    STAGE_WRITE(1, sA0, sA1);  // plane 3 -> slot 1
    STAGE_LOAD(4, sB0, sB1);   // prefetch plane 4
    LDS_YSORT(0, 0);           // Yst0 = plane 2
    WINDOW(1, 2, 0, d0 + 1);

    // ---- zo=2 (planes 1,2,3 -> out d0+2)
    __syncthreads();
    STAGE_WRITE(0, sB0, sB1);  // plane 4 -> slot 0
    LDS_YSORT(1, 1);           // Yst1 = plane 3
    WINDOW(2, 0, 1, d0 + 2);

    // ---- zo=3 (planes 2,3,4 -> out d0+3)
    __syncthreads();
    LDS_YSORT(0, 2);           // Yst2 = plane 4
    WINDOW(0, 1, 2, d0 + 3);

#undef STAGE_LOAD
#undef STAGE_WRITE
#undef LDS_YSORT
#undef LOADDIRECT
#undef WINDOW
}

extern "C" void kernel_launch(void *const *d_in, const int *in_sizes, int n_in,
                              void *d_out, int out_size, void *d_ws,
                              size_t ws_size, hipStream_t stream) {
    const float *x = (const float *)d_in[0];
    float *out = (float *)d_out;
    dim3 block(64, 4, 1);
    dim3 grid(1, 256 / 4, 64 / 4);
    median3d_kernel<<<grid, block, 0, stream>>>(x, out);
}